// Round 3
// baseline (120.630 us; speedup 1.0000x reference)
//
#include <hip/hip_runtime.h>

// Volume rendering composite, faithful to the (unusual) reference semantics:
// cumprod of transmittance runs along the ray-index-within-chunk axis (8192),
// aggregated per (chunk, sample-position p) column. deltas are along p.
//
// Decomposition: s[b,p] = density[b,p] * delta[b,p]  (s >= 0 always:
// sorted depths => delta >= 0, density >= 0). T = exp(-prefix(s)) along the
// chunk-row axis. Three phases:
//   K1: per-segment sums of s            (reads density+depth, 67 MB)
//   K2: exclusive prefix over segments   (wave-parallel scan, ws in L2)
//   K3: per-segment composite + atomicAdd(out). Blocks with all-columns
//       S_base > 110 exit before touching feature: exp(-S)==0 exactly in
//       fp32 (e^-110 ~ 1.7e-48 < min subnormal), and the prefix is monotone,
//       so every skipped contribution is exactly zero.

#define P 128
#define FARD 1.0e10f
#define SKIP_S 110.0f

__global__ __launch_bounds__(64) void seg_sum_kernel(
    const float* __restrict__ density,
    const float* __restrict__ depth,
    float* __restrict__ ws,
    int G, int L, int chunk)
{
    const int g = blockIdx.x, c = blockIdx.y;
    const int t = threadIdx.x;                    // lane 0..63 -> cols 2t, 2t+1
    const long long row0 = (long long)c * chunk + (long long)g * L;
    const float2* __restrict__ d2 = (const float2*)density;
    const float2* __restrict__ z2 = (const float2*)depth;
    float sx = 0.f, sy = 0.f;
    for (int r = 0; r < L; ++r) {
        const long long h = (row0 + r) * (P / 2) + t;
        float2 d = d2[h];
        float2 z = z2[h];
        float zn = __shfl_down(z.x, 1);           // depth[b, 2t+2]
        sx += d.x * (z.y - z.x);                  // delta for col 2t
        sy += d.y * ((t == 63) ? FARD : (zn - z.y)); // col 2t+1 (127 -> FAR)
    }
    float2 o; o.x = sx; o.y = sy;
    ((float2*)ws)[((long long)c * G + g) * (P / 2) + t] = o;
}

// One wave per (chunk, column). Lane l owns G/64 consecutive segment indices;
// serial in-register scan + shfl_up exclusive wave scan of lane totals.
__global__ __launch_bounds__(64) void prefix_kernel(
    float* __restrict__ ws, int G)
{
    const int p = blockIdx.x, c = blockIdx.y;
    const int l = threadIdx.x;
    const int per = G >> 6;                       // G/64, G >= 64 guaranteed
    const long long base = (long long)c * G * P + p;
    float v[16];                                  // per <= 16 (G <= 1024)
    float sum = 0.f;
    for (int k = 0; k < per; ++k) {
        v[k] = ws[base + (long long)(l * per + k) * P];
        sum += v[k];
    }
    float incl = sum;
    for (int off = 1; off < 64; off <<= 1) {
        float n = __shfl_up(incl, off);
        if (l >= off) incl += n;
    }
    float run = incl - sum;                       // exclusive offset for lane
    for (int k = 0; k < per; ++k) {
        float x = v[k];
        ws[base + (long long)(l * per + k) * P] = run;
        run += x;
    }
}

__global__ __launch_bounds__(64) void composite_kernel(
    const float* __restrict__ density,
    const float* __restrict__ feature,
    const float* __restrict__ depth,
    const float* __restrict__ ws,
    float* __restrict__ out,
    int G, int L, int chunk, int n_chunks)
{
    const int g = blockIdx.x, c = blockIdx.y;
    const int t = threadIdx.x;
    float2 S = ((const float2*)ws)[((long long)c * G + g) * (P / 2) + t];
    // Exact skip: prefix monotone non-decreasing; exp(-S)==0 => all later
    // weights in these columns are exactly 0.
    if (__all((S.x > SKIP_S) && (S.y > SKIP_S))) return;

    const long long row0 = (long long)c * chunk + (long long)g * L;
    const float2* __restrict__ d2 = (const float2*)density;
    const float2* __restrict__ z2 = (const float2*)depth;
    const float2* __restrict__ f2 = (const float2*)feature;

    float tx = expf(-S.x), ty = expf(-S.y);       // T at segment start
    float fa0 = 0.f, fa1 = 0.f, fa2 = 0.f;
    float fb0 = 0.f, fb1 = 0.f, fb2 = 0.f;
    float da = 0.f, db = 0.f;

    for (int r = 0; r < L; ++r) {
        const long long h = (row0 + r) * (P / 2) + t;
        float2 d = d2[h];
        float2 z = z2[h];
        float zn = __shfl_down(z.x, 1);
        float sx = d.x * (z.y - z.x);
        float sy = d.y * ((t == 63) ? FARD : (zn - z.y));
        float tempx = expf(-sx);
        float tempy = expf(-sy);
        float wx = tx * (1.f - tempx);            // T_i * (1 - temp_i)
        float wy = ty * (1.f - tempy);
        tx *= tempx;                              // running cumprod, as ref
        ty *= tempy;
        const long long fi = 3 * h;               // float2 index into feature
        float2 f01 = f2[fi], f23 = f2[fi + 1], f45 = f2[fi + 2];
        fa0 += wx * f01.x; fa1 += wx * f01.y; fa2 += wx * f23.x;
        fb0 += wy * f23.y; fb1 += wy * f45.x; fb2 += wy * f45.y;
        da  += wx * z.x;   db  += wy * z.y;
    }

    const int p0 = 2 * t;
    float* fo = out + ((long long)c * P + p0) * 3;
    atomicAdd(fo + 0, fa0); atomicAdd(fo + 1, fa1); atomicAdd(fo + 2, fa2);
    atomicAdd(fo + 3, fb0); atomicAdd(fo + 4, fb1); atomicAdd(fo + 5, fb2);
    float* dp = out + (long long)n_chunks * P * 3 + (long long)c * P + p0;
    atomicAdd(dp + 0, da); atomicAdd(dp + 1, db);
}

extern "C" void kernel_launch(void* const* d_in, const int* in_sizes, int n_in,
                              void* d_out, int out_size, void* d_ws, size_t ws_size,
                              hipStream_t stream)
{
    const float* density = (const float*)d_in[0];
    const float* feature = (const float*)d_in[1];
    const float* depth   = (const float*)d_in[2];
    float* out = (float*)d_out;

    const int B = in_sizes[0] / P;        // 65536
    const int chunk = 8192;               // matches setup_inputs() chunk_size
    const int n_chunks = B / chunk;       // 8

    // Segments per chunk; shrink if workspace is small (keep G >= 64).
    int G = 1024;
    while (G > 64 && (size_t)n_chunks * G * P * sizeof(float) > ws_size) G >>= 1;
    const int L = chunk / G;

    hipMemsetAsync(d_out, 0, (size_t)out_size * sizeof(float), stream);

    dim3 grid(G, n_chunks);
    seg_sum_kernel<<<grid, 64, 0, stream>>>(density, depth, (float*)d_ws,
                                            G, L, chunk);
    dim3 pgrid(P, n_chunks);
    prefix_kernel<<<pgrid, 64, 0, stream>>>((float*)d_ws, G);
    composite_kernel<<<grid, 64, 0, stream>>>(density, feature, depth,
                                              (const float*)d_ws, out,
                                              G, L, chunk, n_chunks);
}

// Round 4
// 69.234 us; speedup vs baseline: 1.7423x; 1.7423x over previous
//
#include <hip/hip_runtime.h>

// Volume rendering composite (cumprod along chunk-row axis, per-column).
// s[b,p] = density*delta >= 0; T = exp(-prefix(s)).
//   K1 seg_sum:   per-segment column sums of s (reads density+depth, 67 MB)
//   K2 prefix:    exclusive prefix over segments (wave scan, ws in L2)
//   K3 composite: 16 waves/block = 16 segments; register accumulate,
//                 LDS tree-reduce, ONE plain 512-float partial store per
//                 block. NO global atomics (prev version: 1.26M device-scope
//                 atomics = 82 us atomic-throughput-bound).
//                 Exact skip: prefix monotone, exp(-S)==0 in fp32 for
//                 S>110 => skipped contributions are exactly zero.
//   K4 reduce:    fixed-order sum of per-block partials -> d_out.

#define P 128
#define FARD 1.0e10f
#define SKIP_S 110.0f
#define SB 16          // segments (waves) per composite block

__global__ __launch_bounds__(256) void seg_sum_kernel(
    const float* __restrict__ density,
    const float* __restrict__ depth,
    float* __restrict__ wsA,
    int G, int L, int chunk)
{
    const int w = threadIdx.x >> 6;               // wave 0..3 -> segment
    const int t = threadIdx.x & 63;               // lane -> cols 2t, 2t+1
    const int g = blockIdx.x * 4 + w;
    const int c = blockIdx.y;
    const long long row0 = (long long)c * chunk + (long long)g * L;
    const float2* __restrict__ d2 = (const float2*)density;
    const float2* __restrict__ z2 = (const float2*)depth;
    float sx = 0.f, sy = 0.f;
    for (int r = 0; r < L; ++r) {
        const long long h = (row0 + r) * (P / 2) + t;
        float2 d = d2[h];
        float2 z = z2[h];
        float zn = __shfl_down(z.x, 1);           // depth[b, 2t+2]
        sx += d.x * (z.y - z.x);
        sy += d.y * ((t == 63) ? FARD : (zn - z.y));
    }
    float2 o; o.x = sx; o.y = sy;
    ((float2*)wsA)[((long long)c * G + g) * (P / 2) + t] = o;
}

// One wave per (chunk, column): lane-blocked serial scan + shfl_up wave scan.
__global__ __launch_bounds__(64) void prefix_kernel(
    float* __restrict__ wsA, int G)
{
    const int p = blockIdx.x, c = blockIdx.y;
    const int l = threadIdx.x;
    const int per = G >> 6;                       // G >= 64
    const long long base = (long long)c * G * P + p;
    float v[16];
    float sum = 0.f;
    for (int k = 0; k < per; ++k) {
        v[k] = wsA[base + (long long)(l * per + k) * P];
        sum += v[k];
    }
    float incl = sum;
    for (int off = 1; off < 64; off <<= 1) {
        float n = __shfl_up(incl, off);
        if (l >= off) incl += n;
    }
    float run = incl - sum;
    for (int k = 0; k < per; ++k) {
        float x = v[k];
        wsA[base + (long long)(l * per + k) * P] = run;
        run += x;
    }
}

__global__ __launch_bounds__(1024) void composite_kernel(
    const float* __restrict__ density,
    const float* __restrict__ feature,
    const float* __restrict__ depth,
    const float* __restrict__ wsA,
    float* __restrict__ wsB,
    int G, int L, int chunk, int nsb)
{
    __shared__ float red[SB * 512];               // 32 KB
    __shared__ int anylive;
    const int w = threadIdx.x >> 6, t = threadIdx.x & 63;
    const int sb = blockIdx.x, c = blockIdx.y;
    const int g = sb * SB + w;

    float2 S = ((const float2*)wsA)[((long long)c * G + g) * (P / 2) + t];
    const bool dead = __all((S.x > SKIP_S) && (S.y > SKIP_S));
    if (threadIdx.x == 0) anylive = 0;
    __syncthreads();
    if (!dead && t == 0) anylive = 1;             // benign same-value race
    __syncthreads();
    if (!anylive) return;                         // partials pre-zeroed

    float fa0 = 0.f, fa1 = 0.f, fa2 = 0.f;
    float fb0 = 0.f, fb1 = 0.f, fb2 = 0.f;
    float da = 0.f, db = 0.f;

    if (!dead) {
        const long long row0 = (long long)c * chunk + (long long)g * L;
        const float2* __restrict__ d2 = (const float2*)density;
        const float2* __restrict__ z2 = (const float2*)depth;
        const float2* __restrict__ f2 = (const float2*)feature;
        float tx = __expf(-S.x), ty = __expf(-S.y);
        tx = expf(-S.x); ty = expf(-S.y);         // keep libm exp (exact path)
        for (int r = 0; r < L; ++r) {
            const long long h = (row0 + r) * (P / 2) + t;
            float2 d = d2[h];
            float2 z = z2[h];
            float zn = __shfl_down(z.x, 1);
            float sx = d.x * (z.y - z.x);
            float sy = d.y * ((t == 63) ? FARD : (zn - z.y));
            float tempx = expf(-sx);
            float tempy = expf(-sy);
            float wx = tx * (1.f - tempx);        // T_i * (1 - temp_i)
            float wy = ty * (1.f - tempy);
            tx *= tempx;                          // running cumprod, as ref
            ty *= tempy;
            const long long fi = 3 * h;
            float2 f01 = f2[fi], f23 = f2[fi + 1], f45 = f2[fi + 2];
            fa0 += wx * f01.x; fa1 += wx * f01.y; fa2 += wx * f23.x;
            fb0 += wy * f23.y; fb1 += wy * f45.x; fb2 += wy * f45.y;
            da  += wx * z.x;   db  += wy * z.y;
        }
    }

    // Per-wave partials -> LDS. Layout per wave: [p*3+comp | 384+p].
    const int p0 = 2 * t;
    float* rw = red + w * 512;
    rw[p0 * 3 + 0] = fa0; rw[p0 * 3 + 1] = fa1; rw[p0 * 3 + 2] = fa2;
    rw[p0 * 3 + 3] = fb0; rw[p0 * 3 + 4] = fb1; rw[p0 * 3 + 5] = fb2;
    rw[384 + p0] = da;    rw[384 + p0 + 1] = db;
    __syncthreads();

    if (threadIdx.x < 512) {
        float s = 0.f;
        #pragma unroll
        for (int k = 0; k < SB; ++k) s += red[k * 512 + threadIdx.x];
        wsB[((long long)c * nsb + sb) * 512 + threadIdx.x] = s;
    }
}

__global__ __launch_bounds__(512) void reduce_kernel(
    const float* __restrict__ wsB,
    float* __restrict__ out,
    int nsb, int n_chunks)
{
    const int c = blockIdx.x, i = threadIdx.x;
    float s = 0.f;
    for (int sb = 0; sb < nsb; ++sb)
        s += wsB[((long long)c * nsb + sb) * 512 + i];
    if (i < 384) out[(long long)c * 384 + i] = s;                    // feat
    else out[(long long)n_chunks * 384 + (long long)c * P + (i - 384)] = s;
}

extern "C" void kernel_launch(void* const* d_in, const int* in_sizes, int n_in,
                              void* d_out, int out_size, void* d_ws, size_t ws_size,
                              hipStream_t stream)
{
    const float* density = (const float*)d_in[0];
    const float* feature = (const float*)d_in[1];
    const float* depth   = (const float*)d_in[2];
    float* out = (float*)d_out;

    const int B = in_sizes[0] / P;        // 65536
    const int chunk = 8192;
    const int n_chunks = B / chunk;       // 8

    int G = 1024;
    while (G > 64) {
        size_t a = (size_t)n_chunks * G * P * 4;
        size_t b = (size_t)n_chunks * (G / SB) * 512 * 4;
        if (a + b <= ws_size) break;
        G >>= 1;
    }
    const int L = chunk / G;
    const int nsb = G / SB;
    float* wsA = (float*)d_ws;
    float* wsB = wsA + (size_t)n_chunks * G * P;

    hipMemsetAsync(wsB, 0, (size_t)n_chunks * nsb * 512 * sizeof(float), stream);

    dim3 g1(G / 4, n_chunks);
    seg_sum_kernel<<<g1, 256, 0, stream>>>(density, depth, wsA, G, L, chunk);
    dim3 g2(P, n_chunks);
    prefix_kernel<<<g2, 64, 0, stream>>>(wsA, G);
    dim3 g3(nsb, n_chunks);
    composite_kernel<<<g3, 1024, 0, stream>>>(density, feature, depth,
                                              wsA, wsB, G, L, chunk, nsb);
    reduce_kernel<<<n_chunks, 512, 0, stream>>>(wsB, out, nsb, n_chunks);
}

// Round 5
// 62.332 us; speedup vs baseline: 1.9353x; 1.1107x over previous
//
#include <hip/hip_runtime.h>

// Volume rendering composite (cumprod along chunk-row axis, per-column).
// s[b,p] = density*delta >= 0; T = exp(-prefix(s)).
//   K1 seg_sum:   per-segment column sums of s (reads density+depth, 67 MB)
//   K2 prefix:    exclusive prefix over segments (wave scan, ws in L2)
//   K3 composite: 16 waves/block = 16 segments; register accumulate,
//                 LDS tree-reduce, ONE plain 512-float partial store per
//                 block. No global atomics, and no memset: dead blocks
//                 store zero partials themselves (hipMemsetAsync's fill
//                 kernel measured 57 us for 1 MB inside the graph).
//                 Exact skip: prefix monotone, exp(-S)==0 in fp32 for
//                 S>110 => skipped contributions are exactly zero.
//   K4 reduce:    fixed-order sum of per-block partials -> d_out.

#define P 128
#define FARD 1.0e10f
#define SKIP_S 110.0f
#define SB 16          // segments (waves) per composite block

__global__ __launch_bounds__(256) void seg_sum_kernel(
    const float* __restrict__ density,
    const float* __restrict__ depth,
    float* __restrict__ wsA,
    int G, int L, int chunk)
{
    const int w = threadIdx.x >> 6;               // wave 0..3 -> segment
    const int t = threadIdx.x & 63;               // lane -> cols 2t, 2t+1
    const int g = blockIdx.x * 4 + w;
    const int c = blockIdx.y;
    const long long row0 = (long long)c * chunk + (long long)g * L;
    const float2* __restrict__ d2 = (const float2*)density;
    const float2* __restrict__ z2 = (const float2*)depth;
    float sx = 0.f, sy = 0.f;
    for (int r = 0; r < L; ++r) {
        const long long h = (row0 + r) * (P / 2) + t;
        float2 d = d2[h];
        float2 z = z2[h];
        float zn = __shfl_down(z.x, 1);           // depth[b, 2t+2]
        sx += d.x * (z.y - z.x);
        sy += d.y * ((t == 63) ? FARD : (zn - z.y));
    }
    float2 o; o.x = sx; o.y = sy;
    ((float2*)wsA)[((long long)c * G + g) * (P / 2) + t] = o;
}

// One wave per (chunk, column): lane-blocked serial scan + shfl_up wave scan.
__global__ __launch_bounds__(64) void prefix_kernel(
    float* __restrict__ wsA, int G)
{
    const int p = blockIdx.x, c = blockIdx.y;
    const int l = threadIdx.x;
    const int per = G >> 6;                       // G >= 64
    const long long base = (long long)c * G * P + p;
    float v[16];
    float sum = 0.f;
    for (int k = 0; k < per; ++k) {
        v[k] = wsA[base + (long long)(l * per + k) * P];
        sum += v[k];
    }
    float incl = sum;
    for (int off = 1; off < 64; off <<= 1) {
        float n = __shfl_up(incl, off);
        if (l >= off) incl += n;
    }
    float run = incl - sum;
    for (int k = 0; k < per; ++k) {
        float x = v[k];
        wsA[base + (long long)(l * per + k) * P] = run;
        run += x;
    }
}

__global__ __launch_bounds__(1024) void composite_kernel(
    const float* __restrict__ density,
    const float* __restrict__ feature,
    const float* __restrict__ depth,
    const float* __restrict__ wsA,
    float* __restrict__ wsB,
    int G, int L, int chunk, int nsb)
{
    __shared__ float red[SB * 512];               // 32 KB
    const int w = threadIdx.x >> 6, t = threadIdx.x & 63;
    const int sb = blockIdx.x, c = blockIdx.y;
    const int g = sb * SB + w;

    float2 S = ((const float2*)wsA)[((long long)c * G + g) * (P / 2) + t];
    const bool dead = __all((S.x > SKIP_S) && (S.y > SKIP_S));

    float fa0 = 0.f, fa1 = 0.f, fa2 = 0.f;
    float fb0 = 0.f, fb1 = 0.f, fb2 = 0.f;
    float da = 0.f, db = 0.f;

    if (!dead) {
        const long long row0 = (long long)c * chunk + (long long)g * L;
        const float2* __restrict__ d2 = (const float2*)density;
        const float2* __restrict__ z2 = (const float2*)depth;
        const float2* __restrict__ f2 = (const float2*)feature;
        float tx = expf(-S.x), ty = expf(-S.y);   // T at segment start
        for (int r = 0; r < L; ++r) {
            const long long h = (row0 + r) * (P / 2) + t;
            float2 d = d2[h];
            float2 z = z2[h];
            float zn = __shfl_down(z.x, 1);
            float sx = d.x * (z.y - z.x);
            float sy = d.y * ((t == 63) ? FARD : (zn - z.y));
            float tempx = expf(-sx);
            float tempy = expf(-sy);
            float wx = tx * (1.f - tempx);        // T_i * (1 - temp_i)
            float wy = ty * (1.f - tempy);
            tx *= tempx;                          // running cumprod, as ref
            ty *= tempy;
            const long long fi = 3 * h;
            float2 f01 = f2[fi], f23 = f2[fi + 1], f45 = f2[fi + 2];
            fa0 += wx * f01.x; fa1 += wx * f01.y; fa2 += wx * f23.x;
            fb0 += wy * f23.y; fb1 += wy * f45.x; fb2 += wy * f45.y;
            da  += wx * z.x;   db  += wy * z.y;
        }
    }

    // Per-wave partials -> LDS. Layout per wave: [p*3+comp | 384+p].
    const int p0 = 2 * t;
    float* rw = red + w * 512;
    rw[p0 * 3 + 0] = fa0; rw[p0 * 3 + 1] = fa1; rw[p0 * 3 + 2] = fa2;
    rw[p0 * 3 + 3] = fb0; rw[p0 * 3 + 4] = fb1; rw[p0 * 3 + 5] = fb2;
    rw[384 + p0] = da;    rw[384 + p0 + 1] = db;
    __syncthreads();

    if (threadIdx.x < 512) {
        float s = 0.f;
        #pragma unroll
        for (int k = 0; k < SB; ++k) s += red[k * 512 + threadIdx.x];
        wsB[((long long)c * nsb + sb) * 512 + threadIdx.x] = s;
    }
}

__global__ __launch_bounds__(512) void reduce_kernel(
    const float* __restrict__ wsB,
    float* __restrict__ out,
    int nsb, int n_chunks)
{
    const int c = blockIdx.x, i = threadIdx.x;
    float s = 0.f;
    for (int sb = 0; sb < nsb; ++sb)
        s += wsB[((long long)c * nsb + sb) * 512 + i];
    if (i < 384) out[(long long)c * 384 + i] = s;                    // feat
    else out[(long long)n_chunks * 384 + (long long)c * P + (i - 384)] = s;
}

extern "C" void kernel_launch(void* const* d_in, const int* in_sizes, int n_in,
                              void* d_out, int out_size, void* d_ws, size_t ws_size,
                              hipStream_t stream)
{
    const float* density = (const float*)d_in[0];
    const float* feature = (const float*)d_in[1];
    const float* depth   = (const float*)d_in[2];
    float* out = (float*)d_out;

    const int B = in_sizes[0] / P;        // 65536
    const int chunk = 8192;
    const int n_chunks = B / chunk;       // 8

    int G = 1024;
    while (G > 64) {
        size_t a = (size_t)n_chunks * G * P * 4;
        size_t b = (size_t)n_chunks * (G / SB) * 512 * 4;
        if (a + b <= ws_size) break;
        G >>= 1;
    }
    const int L = chunk / G;
    const int nsb = G / SB;
    float* wsA = (float*)d_ws;
    float* wsB = wsA + (size_t)n_chunks * G * P;

    dim3 g1(G / 4, n_chunks);
    seg_sum_kernel<<<g1, 256, 0, stream>>>(density, depth, wsA, G, L, chunk);
    dim3 g2(P, n_chunks);
    prefix_kernel<<<g2, 64, 0, stream>>>(wsA, G);
    dim3 g3(nsb, n_chunks);
    composite_kernel<<<g3, 1024, 0, stream>>>(density, feature, depth,
                                              wsA, wsB, G, L, chunk, nsb);
    reduce_kernel<<<n_chunks, 512, 0, stream>>>(wsB, out, nsb, n_chunks);
}

// Round 6
// 39.835 us; speedup vs baseline: 3.0282x; 1.5647x over previous
//
#include <hip/hip_runtime.h>

// Volume rendering composite (cumprod along chunk-row axis, per-column).
// s[b,p] = density*delta >= 0; T = exp(-prefix(s)); monotone prefix =>
// exp(-S)==0 exactly in fp32 for S>110, so late contributions are exactly 0.
//
// 3-kernel structure (prev 4-kernel version: uncoalesced prefix scan +
// 64-wave reduce + extra dispatch cost ~45 us of non-BW time):
//   K1 seg_sum:   per-segment (8-row) column sums -> wsA, plus per-block
//                 (64-row superblock) sums via LDS reduce -> wsBS.
//   K2 composite: block (sb,c) rebuilds its prefix base from <=127 coalesced
//                 L2-resident superblock sums (fixed order) + intra-block
//                 segment prefix in LDS; live waves composite with __expf;
//                 LDS tree-reduce; ONE plain 512-float partial store.
//                 No atomics, no memset (dead blocks write zero partials).
//   K3 reduce:    fixed-order sum over 128 partials -> d_out.

#define P 128
#define FARD 1.0e10f
#define SKIP_S 110.0f
#define SB 8           // segments (waves) per block
#define LROWS 8        // rows per segment; superblock = 64 rows

__global__ __launch_bounds__(512) void seg_sum_kernel(
    const float* __restrict__ density,
    const float* __restrict__ depth,
    float* __restrict__ wsA,    // [c][g][P] per-segment sums
    float* __restrict__ wsBS,   // [c][sb][P] superblock sums
    int G, int nsb, int chunk)
{
    __shared__ float2 ls[SB][64];
    const int w = threadIdx.x >> 6;               // segment within block
    const int t = threadIdx.x & 63;               // lane -> cols 2t, 2t+1
    const int sb = blockIdx.x, c = blockIdx.y;
    const int g = sb * SB + w;
    const long long row0 = (long long)c * chunk + (long long)g * LROWS;
    const float2* __restrict__ d2 = (const float2*)density;
    const float2* __restrict__ z2 = (const float2*)depth;
    float sx = 0.f, sy = 0.f;
    for (int r = 0; r < LROWS; ++r) {
        const long long h = (row0 + r) * (P / 2) + t;
        float2 d = d2[h];
        float2 z = z2[h];
        float zn = __shfl_down(z.x, 1);           // depth[b, 2t+2]
        sx += d.x * (z.y - z.x);
        sy += d.y * ((t == 63) ? FARD : (zn - z.y));
    }
    float2 o; o.x = sx; o.y = sy;
    ((float2*)wsA)[((long long)c * G + g) * (P / 2) + t] = o;
    ls[w][t] = o;
    __syncthreads();
    if (w == 0) {
        float bx = 0.f, by = 0.f;
        #pragma unroll
        for (int k = 0; k < SB; ++k) { bx += ls[k][t].x; by += ls[k][t].y; }
        float2 b; b.x = bx; b.y = by;
        ((float2*)wsBS)[((long long)c * nsb + sb) * (P / 2) + t] = b;
    }
}

__global__ __launch_bounds__(512) void composite_kernel(
    const float* __restrict__ density,
    const float* __restrict__ feature,
    const float* __restrict__ depth,
    const float* __restrict__ wsA,
    const float* __restrict__ wsBS,
    float* __restrict__ wsB,    // [c][sb][512] partials
    int G, int nsb, int chunk)
{
    __shared__ float part[4][P];
    __shared__ float base[P];
    __shared__ float seg[SB][P];
    __shared__ float red[SB][512];
    const int tid = threadIdx.x;
    const int w = tid >> 6, t = tid & 63;
    const int sb = blockIdx.x, c = blockIdx.y;

    // base[p] = sum_{sb'<sb} wsBS[c][sb'][p], fixed-order 4-way split.
    {
        const int p = tid & (P - 1), j = tid >> 7;        // j = 0..3
        float s = 0.f;
        for (int sbp = j; sbp < sb; sbp += 4)
            s += wsBS[((long long)c * nsb + sbp) * P + p];
        part[j][p] = s;
    }
    // Own 8 segment sums -> LDS (2 coalesced loads per thread).
    {
        int idx = tid;
        int w2 = idx >> 7, p2 = idx & (P - 1);
        seg[w2][p2] = wsA[((long long)c * G + sb * SB + w2) * P + p2];
        idx += 512; w2 = idx >> 7; p2 = idx & (P - 1);
        seg[w2][p2] = wsA[((long long)c * G + sb * SB + w2) * P + p2];
    }
    __syncthreads();
    if (tid < P)
        base[tid] = (part[0][tid] + part[1][tid]) + (part[2][tid] + part[3][tid]);
    __syncthreads();

    const int p0 = 2 * t;
    float Sx = base[p0], Sy = base[p0 + 1];
    for (int k = 0; k < w; ++k) { Sx += seg[k][p0]; Sy += seg[k][p0 + 1]; }

    float fa0 = 0.f, fa1 = 0.f, fa2 = 0.f;
    float fb0 = 0.f, fb1 = 0.f, fb2 = 0.f;
    float da = 0.f, db = 0.f;

    const bool dead = __all((Sx > SKIP_S) && (Sy > SKIP_S));
    if (!dead) {
        const int g = sb * SB + w;
        const long long row0 = (long long)c * chunk + (long long)g * LROWS;
        const float2* __restrict__ d2 = (const float2*)density;
        const float2* __restrict__ z2 = (const float2*)depth;
        const float2* __restrict__ f2 = (const float2*)feature;
        float tx = __expf(-Sx), ty = __expf(-Sy);  // T at segment start
        for (int r = 0; r < LROWS; ++r) {
            const long long h = (row0 + r) * (P / 2) + t;
            float2 d = d2[h];
            float2 z = z2[h];
            float zn = __shfl_down(z.x, 1);
            float sx = d.x * (z.y - z.x);
            float sy = d.y * ((t == 63) ? FARD : (zn - z.y));
            float ex = __expf(-sx), ey = __expf(-sy);
            float wx = tx * (1.f - ex);           // T_i * (1 - temp_i)
            float wy = ty * (1.f - ey);
            tx *= ex; ty *= ey;                   // running cumprod, as ref
            const long long fi = 3 * h;
            float2 f01 = f2[fi], f23 = f2[fi + 1], f45 = f2[fi + 2];
            fa0 += wx * f01.x; fa1 += wx * f01.y; fa2 += wx * f23.x;
            fb0 += wy * f23.y; fb1 += wy * f45.x; fb2 += wy * f45.y;
            da  += wx * z.x;   db  += wy * z.y;
        }
    }

    // Per-wave partials -> LDS. Layout per wave: [p*3+comp | 384+p].
    float* rw = red[w];
    rw[p0 * 3 + 0] = fa0; rw[p0 * 3 + 1] = fa1; rw[p0 * 3 + 2] = fa2;
    rw[p0 * 3 + 3] = fb0; rw[p0 * 3 + 4] = fb1; rw[p0 * 3 + 5] = fb2;
    rw[384 + p0] = da;    rw[384 + p0 + 1] = db;
    __syncthreads();

    float s = 0.f;
    #pragma unroll
    for (int k = 0; k < SB; ++k) s += red[k][tid];
    wsB[((long long)c * nsb + sb) * 512 + tid] = s;
}

__global__ __launch_bounds__(64) void reduce_kernel(
    const float* __restrict__ wsB,
    float* __restrict__ out,
    int nsb, int n_chunks)
{
    const int b = blockIdx.x;                     // 8 blocks per chunk
    const int c = b >> 3, q = b & 7;
    const int e = q * 64 + threadIdx.x;           // 0..511
    float s = 0.f;
    #pragma unroll 4
    for (int sb = 0; sb < nsb; ++sb)
        s += wsB[((long long)c * nsb + sb) * 512 + e];
    if (e < 384) out[(long long)c * 384 + e] = s;                    // feat
    else out[(long long)n_chunks * 384 + (long long)c * P + (e - 384)] = s;
}

extern "C" void kernel_launch(void* const* d_in, const int* in_sizes, int n_in,
                              void* d_out, int out_size, void* d_ws, size_t ws_size,
                              hipStream_t stream)
{
    const float* density = (const float*)d_in[0];
    const float* feature = (const float*)d_in[1];
    const float* depth   = (const float*)d_in[2];
    float* out = (float*)d_out;

    const int B = in_sizes[0] / P;        // 65536
    const int chunk = 8192;               // matches setup_inputs() chunk_size
    const int n_chunks = B / chunk;       // 8
    const int nsb = chunk / (SB * LROWS); // 128 superblocks per chunk
    const int G = nsb * SB;               // 1024 segments per chunk

    float* wsA  = (float*)d_ws;                          // 4 MB
    float* wsBS = wsA + (size_t)n_chunks * G * P;        // 0.5 MB
    float* wsB  = wsBS + (size_t)n_chunks * nsb * P;     // 2 MB

    dim3 grid(nsb, n_chunks);
    seg_sum_kernel<<<grid, 512, 0, stream>>>(density, depth, wsA, wsBS,
                                             G, nsb, chunk);
    composite_kernel<<<grid, 512, 0, stream>>>(density, feature, depth,
                                               wsA, wsBS, wsB, G, nsb, chunk);
    reduce_kernel<<<n_chunks * 8, 64, 0, stream>>>(wsB, out, nsb, n_chunks);
}